// Round 10
// baseline (155.414 us; speedup 1.0000x reference)
//
#include <hip/hip_runtime.h>
#include <hip/hip_fp16.h>

#define GRID_RES 128
#define N_RAYS 65536
#define N_STEPS 128
#define STEP_SIZE 0.001f
#define NVOX (GRID_RES * GRID_RES * GRID_RES)   // 2097152

__device__ __forceinline__ float rcp_fast(float x) {
    return __builtin_amdgcn_rcpf(x);   // v_rcp_f32, ~1 ulp
}
__device__ __forceinline__ float sigmoidf_fast(float x) {
    return rcp_fast(1.0f + __expf(-x));
}

// DPP quad_perm helpers (cross-lane within aligned groups of 4 lanes)
__device__ __forceinline__ float quad_dpp_xor1(float x) {
    return __int_as_float(__builtin_amdgcn_update_dpp(0, __float_as_int(x), 0xB1, 0xF, 0xF, true)); // [1,0,3,2]
}
__device__ __forceinline__ float quad_dpp_xor2(float x) {
    return __int_as_float(__builtin_amdgcn_update_dpp(0, __float_as_int(x), 0x4E, 0xF, 0xF, true)); // [2,3,0,1]
}
__device__ __forceinline__ float quad_bcast3(float x) {
    return __int_as_float(__builtin_amdgcn_update_dpp(0, __float_as_int(x), 0xFF, 0xF, 0xF, true)); // [3,3,3,3]
}
__device__ __forceinline__ float quad_sum(float x) {
    x += quad_dpp_xor1(x);
    x += quad_dpp_xor2(x);
    return x;
}

__device__ __forceinline__ unsigned pack2(float a, float b) {
    return ((unsigned)__half_as_ushort(__float2half(b)) << 16)
         |  (unsigned)__half_as_ushort(__float2half(a));
}

// ---- prepass: repack 112B f32 records -> 64B-aligned fp16 records in ws ----
// halves 0..26 = coeffs, half 27 = relu(sigma), halves 28..31 = 0 pad.
// 128 MiB total -> resident in Infinity Cache for the render phase.
__global__ __launch_bounds__(256) void repack_kernel(
    const float* __restrict__ data, uint4* __restrict__ packed)
{
    unsigned v = blockIdx.x * 256u + threadIdx.x;   // grid sized exactly NVOX
    const float4* rec = (const float4*)(data + 28u * v);
    float4 c0 = rec[0], c1 = rec[1], c2 = rec[2], c3 = rec[3],
           c4 = rec[4], c5 = rec[5], c6 = rec[6];
    float sig = fmaxf(c6.w, 0.0f);    // relu pre-applied (monotone, exact)

    uint4 q0, q1, q2, q3;
    q0.x = pack2(c0.x, c0.y); q0.y = pack2(c0.z, c0.w);
    q0.z = pack2(c1.x, c1.y); q0.w = pack2(c1.z, c1.w);
    q1.x = pack2(c2.x, c2.y); q1.y = pack2(c2.z, c2.w);
    q1.z = pack2(c3.x, c3.y); q1.w = pack2(c3.z, c3.w);
    q2.x = pack2(c4.x, c4.y); q2.y = pack2(c4.z, c4.w);
    q2.z = pack2(c5.x, c5.y); q2.w = pack2(c5.z, c5.w);
    q3.x = pack2(c6.x, c6.y); q3.y = pack2(c6.z, sig);
    q3.z = 0u; q3.w = 0u;

    uint4* dst = packed + 4u * v;
    dst[0] = q0; dst[1] = q1; dst[2] = q2; dst[3] = q3;
}

__global__ __launch_bounds__(256, 4) void vr_kernel(
    const uint4* __restrict__ packed,
    const float* __restrict__ origins,
    const float* __restrict__ dirs,
    const float* __restrict__ viewdirs,
    float* __restrict__ out)
{
    int gid = blockIdx.x * blockDim.x + threadIdx.x;
    int ray = gid >> 2;        // 4 cooperative lanes per ray
    int l   = gid & 3;

    float ox = origins[3*ray+0], oy = origins[3*ray+1], oz = origins[3*ray+2];
    float dx = dirs[3*ray+0],    dy = dirs[3*ray+1],    dz = dirs[3*ray+2];
    float vx = viewdirs[3*ray+0], vy = viewdirs[3*ray+1], vz = viewdirs[3*ray+2];

    // normalize (numpy rounding: no fma contraction, sqrt+divide)
    {
        float s = __fadd_rn(__fadd_rn(__fmul_rn(dx,dx), __fmul_rn(dy,dy)), __fmul_rn(dz,dz));
        float n = sqrtf(s);
        dx = __fdiv_rn(dx, n); dy = __fdiv_rn(dy, n); dz = __fdiv_rn(dz, n);
    }
    {
        float s = __fadd_rn(__fadd_rn(__fmul_rn(vx,vx), __fmul_rn(vy,vy)), __fmul_rn(vz,vz));
        float n = sqrtf(s);
        vx = __fdiv_rn(vx, n); vy = __fdiv_rn(vy, n); vz = __fdiv_rn(vz, n);
    }

    float invx = __fdiv_rn(1.0f, __fadd_rn(dx, 1e-9f));
    float invy = __fdiv_rn(1.0f, __fadd_rn(dy, 1e-9f));
    float invz = __fdiv_rn(1.0f, __fadd_rn(dz, 1e-9f));

    float t1x = __fmul_rn(-ox, invx), t1y = __fmul_rn(-oy, invy), t1z = __fmul_rn(-oz, invz);
    float t2x = __fadd_rn(t1x, invx), t2y = __fadd_rn(t1y, invy), t2z = __fadd_rn(t1z, invz);
    float tmin = fmaxf(fmaxf(fminf(t1x,t2x), fminf(t1y,t2y)), fminf(t1z,t2z));
    tmin = fmaxf(tmin, 0.0f);
    float tmax = fminf(fminf(fmaxf(t1x,t2x), fmaxf(t1y,t2y)), fmaxf(t1z,t2z));
    tmax = fminf(tmax, 1e9f);
    float dt = __fmul_rn(fmaxf(__fsub_rn(tmax, tmin), 0.0f), (1.0f/(float)N_STEPS));
    float delta_t = __fadd_rn(dt, STEP_SIZE);

    // SH basis
    const float sh0 = 0.28209479177387814f;
    float sh1 = -0.4886025119029199f * vy;
    float sh2 =  0.4886025119029199f * vz;
    float sh3 = -0.4886025119029199f * vx;
    float sh4 =  1.0925484305920792f * vx * vy;
    float sh5 = -1.0925484305920792f * vy * vz;
    float sh6 =  0.31539156525252005f * (2.0f*vz*vz - vx*vx - vy*vy);
    float sh7 = -1.0925484305920792f * vx * vz;
    float sh8 =  0.5462742152960396f * (vx*vx - vy*vy);

    // Per-lane channel-routed weights for comps c = 8l..8l+7 (c>=27 -> all zero).
    float wr[8], wg_[8], wb[8];
    #pragma unroll
    for (int m = 0; m < 8; ++m) {
        int c  = 8*l + m;
        int cb = c % 9;
        float s = sh0;
        s = (cb==1) ? sh1 : s;
        s = (cb==2) ? sh2 : s;
        s = (cb==3) ? sh3 : s;
        s = (cb==4) ? sh4 : s;
        s = (cb==5) ? sh5 : s;
        s = (cb==6) ? sh6 : s;
        s = (cb==7) ? sh7 : s;
        s = (cb==8) ? sh8 : s;
        wr[m]  = (c < 9)            ? s : 0.0f;
        wg_[m] = (c >= 9 && c < 18) ? s : 0.0f;
        wb[m]  = (c >= 18 && c < 27)? s : 0.0f;
    }

    // voxel linear index for step i — bit-identical to the validated chain
    auto linidx = [&](int i) -> unsigned {
        float t = __fadd_rn(tmin, __fmul_rn((float)i + 0.5f, dt));
        float px = __fadd_rn(ox, __fmul_rn(t, dx));
        float py = __fadd_rn(oy, __fmul_rn(t, dy));
        float pz = __fadd_rn(oz, __fmul_rn(t, dz));
        int ix = (int)(px * (float)GRID_RES);
        int iy = (int)(py * (float)GRID_RES);
        int iz = (int)(pz * (float)GRID_RES);
        ix = min(max(ix, 0), GRID_RES-1);
        iy = min(max(iy, 0), GRID_RES-1);
        iz = min(max(iz, 0), GRID_RES-1);
        return (unsigned)(((ix << 7) | iy) << 7 | iz);
    };

    float light = 1.0f;
    float o_r = 0.0f, o_g = 0.0f, o_b = 0.0f;

    #pragma unroll 4
    for (int i = 0; i < N_STEPS; ++i) {
        unsigned lin = linidx(i);
        // one 16B load per lane; the quad's 4 loads = one 64B sector
        uint4 q = packed[4u * lin + (unsigned)l];

        float f0 = __half2float(__ushort_as_half((unsigned short)(q.x)));
        float f1 = __half2float(__ushort_as_half((unsigned short)(q.x >> 16)));
        float f2 = __half2float(__ushort_as_half((unsigned short)(q.y)));
        float f3 = __half2float(__ushort_as_half((unsigned short)(q.y >> 16)));
        float f4 = __half2float(__ushort_as_half((unsigned short)(q.z)));
        float f5 = __half2float(__ushort_as_half((unsigned short)(q.z >> 16)));
        float f6 = __half2float(__ushort_as_half((unsigned short)(q.w)));
        float f7 = __half2float(__ushort_as_half((unsigned short)(q.w >> 16)));

        // sigma: lane3's f3 = half 27 = relu(sigma), broadcast to the quad
        float sigma = quad_bcast3(f3);
        float att = __expf(-delta_t * sigma);
        float w = light * (1.0f - att);

        float pr = wr[0]*f0 + wr[1]*f1 + wr[2]*f2 + wr[3]*f3
                 + wr[4]*f4 + wr[5]*f5 + wr[6]*f6 + wr[7]*f7;
        float pg = wg_[0]*f0 + wg_[1]*f1 + wg_[2]*f2 + wg_[3]*f3
                 + wg_[4]*f4 + wg_[5]*f5 + wg_[6]*f6 + wg_[7]*f7;
        float pb = wb[0]*f0 + wb[1]*f1 + wb[2]*f2 + wb[3]*f3
                 + wb[4]*f4 + wb[5]*f5 + wb[6]*f6 + wb[7]*f7;

        float r = quad_sum(pr);
        float g = quad_sum(pg);
        float b = quad_sum(pb);

        o_r = fmaf(w, sigmoidf_fast(r), o_r);
        o_g = fmaf(w, sigmoidf_fast(g), o_g);
        o_b = fmaf(w, sigmoidf_fast(b), o_b);
        light *= att;
    }

    if (l == 0) {
        out[3*ray+0] = o_r + light;   // BG = 1.0
        out[3*ray+1] = o_g + light;
        out[3*ray+2] = o_b + light;
    }
}

extern "C" void kernel_launch(void* const* d_in, const int* in_sizes, int n_in,
                              void* d_out, int out_size, void* d_ws, size_t ws_size,
                              hipStream_t stream) {
    const float* data     = (const float*)d_in[0];
    const float* origins  = (const float*)d_in[1];
    const float* dirs     = (const float*)d_in[2];
    const float* viewdirs = (const float*)d_in[3];
    float* out = (float*)d_out;

    // ws: fp16-packed grid, NVOX x 64B = 128 MiB (< L3). Fully rewritten
    // every launch (pure function of data) -> deterministic, poison-safe.
    uint4* packed = (uint4*)d_ws;

    repack_kernel<<<NVOX / 256, 256, 0, stream>>>(data, packed);
    vr_kernel<<<(N_RAYS * 4) / 256, 256, 0, stream>>>(packed, origins, dirs, viewdirs, out);
}

// Round 11
// 116.496 us; speedup vs baseline: 1.3341x; 1.3341x over previous
//
#include <hip/hip_runtime.h>

#define GRID_RES 128
#define N_RAYS 65536
#define N_STEPS 128
#define STEP_SIZE 0.001f

__device__ __forceinline__ float rcp_fast(float x) {
    return __builtin_amdgcn_rcpf(x);   // v_rcp_f32, ~1 ulp
}
__device__ __forceinline__ float sigmoidf_fast(float x) {
    return rcp_fast(1.0f + __expf(-x));
}

// DPP quad_perm helpers (cross-lane within aligned groups of 4 lanes)
__device__ __forceinline__ float quad_dpp_xor1(float x) {
    return __int_as_float(__builtin_amdgcn_update_dpp(0, __float_as_int(x), 0xB1, 0xF, 0xF, true)); // [1,0,3,2]
}
__device__ __forceinline__ float quad_dpp_xor2(float x) {
    return __int_as_float(__builtin_amdgcn_update_dpp(0, __float_as_int(x), 0x4E, 0xF, 0xF, true)); // [2,3,0,1]
}
__device__ __forceinline__ float quad_sum(float x) {
    x += quad_dpp_xor1(x);
    x += quad_dpp_xor2(x);
    return x;
}

__global__ __launch_bounds__(256) void vr_kernel(
    const float* __restrict__ data,
    const float* __restrict__ origins,
    const float* __restrict__ dirs,
    const float* __restrict__ viewdirs,
    float* __restrict__ out)
{
    int gid = blockIdx.x * blockDim.x + threadIdx.x;
    int ray = gid >> 2;        // 4 cooperative lanes per ray
    int l   = gid & 3;

    float ox = origins[3*ray+0], oy = origins[3*ray+1], oz = origins[3*ray+2];
    float dx = dirs[3*ray+0],    dy = dirs[3*ray+1],    dz = dirs[3*ray+2];
    float vx = viewdirs[3*ray+0], vy = viewdirs[3*ray+1], vz = viewdirs[3*ray+2];

    // normalize (numpy rounding: no fma contraction, sqrt+divide)
    {
        float s = __fadd_rn(__fadd_rn(__fmul_rn(dx,dx), __fmul_rn(dy,dy)), __fmul_rn(dz,dz));
        float n = sqrtf(s);
        dx = __fdiv_rn(dx, n); dy = __fdiv_rn(dy, n); dz = __fdiv_rn(dz, n);
    }
    {
        float s = __fadd_rn(__fadd_rn(__fmul_rn(vx,vx), __fmul_rn(vy,vy)), __fmul_rn(vz,vz));
        float n = sqrtf(s);
        vx = __fdiv_rn(vx, n); vy = __fdiv_rn(vy, n); vz = __fdiv_rn(vz, n);
    }

    float invx = __fdiv_rn(1.0f, __fadd_rn(dx, 1e-9f));
    float invy = __fdiv_rn(1.0f, __fadd_rn(dy, 1e-9f));
    float invz = __fdiv_rn(1.0f, __fadd_rn(dz, 1e-9f));

    float t1x = __fmul_rn(-ox, invx), t1y = __fmul_rn(-oy, invy), t1z = __fmul_rn(-oz, invz);
    float t2x = __fadd_rn(t1x, invx), t2y = __fadd_rn(t1y, invy), t2z = __fadd_rn(t1z, invz);
    float tmin = fmaxf(fmaxf(fminf(t1x,t2x), fminf(t1y,t2y)), fminf(t1z,t2z));
    tmin = fmaxf(tmin, 0.0f);
    float tmax = fminf(fminf(fmaxf(t1x,t2x), fmaxf(t1y,t2y)), fmaxf(t1z,t2z));
    tmax = fminf(tmax, 1e9f);
    float dt = __fmul_rn(fmaxf(__fsub_rn(tmax, tmin), 0.0f), (1.0f/(float)N_STEPS));
    float delta_t = __fadd_rn(dt, STEP_SIZE);

    // SH basis
    const float sh0 = 0.28209479177387814f;
    float sh1 = -0.4886025119029199f * vy;
    float sh2 =  0.4886025119029199f * vz;
    float sh3 = -0.4886025119029199f * vx;
    float sh4 =  1.0925484305920792f * vx * vy;
    float sh5 = -1.0925484305920792f * vy * vz;
    float sh6 =  0.31539156525252005f * (2.0f*vz*vz - vx*vx - vy*vy);
    float sh7 = -1.0925484305920792f * vx * vz;
    float sh8 =  0.5462742152960396f * (vx*vx - vy*vy);

    // Per-lane channel-routed weights for components c = 8l..8l+7 (zeros off-channel).
    float wr[8], wg_[8], wb[8];
    #pragma unroll
    for (int m = 0; m < 8; ++m) {
        int c  = 8*l + m;
        int cb = c % 9;
        float s = sh0;
        s = (cb==1) ? sh1 : s;
        s = (cb==2) ? sh2 : s;
        s = (cb==3) ? sh3 : s;
        s = (cb==4) ? sh4 : s;
        s = (cb==5) ? sh5 : s;
        s = (cb==6) ? sh6 : s;
        s = (cb==7) ? sh7 : s;
        s = (cb==8) ? sh8 : s;
        wr[m]  = (c < 9)            ? s : 0.0f;
        wg_[m] = (c >= 9 && c < 18) ? s : 0.0f;
        wb[m]  = (c >= 18 && c < 27)? s : 0.0f;
    }

    unsigned offA = 8u * (unsigned)l;
    unsigned offB = (l < 3) ? (8u * (unsigned)l + 4u) : 24u;

    // voxel linear index for step i — bit-identical to the validated chain
    auto linidx = [&](int i) -> unsigned {
        float t = __fadd_rn(tmin, __fmul_rn((float)i + 0.5f, dt));
        float px = __fadd_rn(ox, __fmul_rn(t, dx));
        float py = __fadd_rn(oy, __fmul_rn(t, dy));
        float pz = __fadd_rn(oz, __fmul_rn(t, dz));
        int ix = (int)(px * (float)GRID_RES);
        int iy = (int)(py * (float)GRID_RES);
        int iz = (int)(pz * (float)GRID_RES);
        ix = min(max(ix, 0), GRID_RES-1);
        iy = min(max(iy, 0), GRID_RES-1);
        iz = min(max(iz, 0), GRID_RES-1);
        return (unsigned)(((ix << 7) | iy) << 7 | iz);
    };

    float light = 1.0f;
    float o_r = 0.0f, o_g = 0.0f, o_b = 0.0f;

    // ---- 3-stage pipeline: sigma(i+2) || gated coeffs(i+1) || shade(i) ----
    // sigma: 4B load, same address across the quad (one sector).
    // coeffs: address redirected to hot array base when sigma<=0.
    unsigned lin1;
    float s0, s1;
    float4 A0, B0;
    {
        unsigned lin0 = linidx(0);
        lin1 = linidx(1);
        s0 = data[28u * lin0 + 27u];
        s1 = data[28u * lin1 + 27u];
        const float* rec0 = (s0 > 0.0f) ? (data + 28u * lin0) : data;
        A0 = *(const float4*)(rec0 + offA);
        B0 = *(const float4*)(rec0 + offB);
    }

    for (int i = 0; i < N_STEPS; ++i) {
        // stage 1: sigma two steps ahead (clamped index math is safe past 127)
        unsigned lin2 = linidx(i + 2);
        float s2 = data[28u * lin2 + 27u];

        // stage 2: coefficients one step ahead, σ-gated via address select
        const float* rec1 = (s1 > 0.0f) ? (data + 28u * lin1) : data;
        float4 A1 = *(const float4*)(rec1 + offA);
        float4 B1 = *(const float4*)(rec1 + offB);

        // stage 3: shade step i (branchless — w==0 exactly when s0<=0)
        float sigma = fmaxf(s0, 0.0f);
        float att = __expf(-delta_t * sigma);
        float w = light * (1.0f - att);

        float pr = wr[0]*A0.x + wr[1]*A0.y + wr[2]*A0.z + wr[3]*A0.w
                 + wr[4]*B0.x + wr[5]*B0.y + wr[6]*B0.z + wr[7]*B0.w;
        float pg = wg_[0]*A0.x + wg_[1]*A0.y + wg_[2]*A0.z + wg_[3]*A0.w
                 + wg_[4]*B0.x + wg_[5]*B0.y + wg_[6]*B0.z + wg_[7]*B0.w;
        float pb = wb[0]*A0.x + wb[1]*A0.y + wb[2]*A0.z + wb[3]*A0.w
                 + wb[4]*B0.x + wb[5]*B0.y + wb[6]*B0.z + wb[7]*B0.w;

        float r = quad_sum(pr);
        float g = quad_sum(pg);
        float b = quad_sum(pb);

        o_r = fmaf(w, sigmoidf_fast(r), o_r);
        o_g = fmaf(w, sigmoidf_fast(g), o_g);
        o_b = fmaf(w, sigmoidf_fast(b), o_b);
        light *= att;

        // shift pipeline (all static — no dynamic register indexing)
        s0 = s1; s1 = s2;
        lin1 = lin2;
        A0 = A1; B0 = B1;
    }

    if (l == 0) {
        out[3*ray+0] = o_r + light;   // BG = 1.0
        out[3*ray+1] = o_g + light;
        out[3*ray+2] = o_b + light;
    }
}

extern "C" void kernel_launch(void* const* d_in, const int* in_sizes, int n_in,
                              void* d_out, int out_size, void* d_ws, size_t ws_size,
                              hipStream_t stream) {
    const float* data     = (const float*)d_in[0];
    const float* origins  = (const float*)d_in[1];
    const float* dirs     = (const float*)d_in[2];
    const float* viewdirs = (const float*)d_in[3];
    float* out = (float*)d_out;

    dim3 block(256);
    dim3 grid((N_RAYS * 4) / 256);
    vr_kernel<<<grid, block, 0, stream>>>(data, origins, dirs, viewdirs, out);
}